// Round 14
// baseline (25.950 us; speedup 1.0000x reference)
//
#include <hip/hip_runtime.h>

// Problem constants (setup_inputs: [16, 3, 512, 512] fp32)
#define HW       262144     // 512*512
#define HWV      65536      // HW/4: float4 vecs per channel-image
#define CH       HW         // channel stride (elements)
#define BSTRIDE  (3*HW)     // batch stride (elements)
#define NELEM_INV (1.0f / 12582912.0f)   // 1 / (16*3*512*512)

#define GRID1    2048
#define BLOCK1   256
// Each thread: 2 ADJACENT f4 per stream (32B/lane) -> 12 outstanding loads/thread.
// Block covers 512 vecs = 2048 elems/stream; 512 | HWV -> no image straddle.

typedef float f4 __attribute__((ext_vector_type(4)));
typedef float f2 __attribute__((ext_vector_type(2)));

__device__ __forceinline__ f4 vload(const float* p) {
    return *reinterpret_cast<const f4*>(p);   // global_load_dwordx4 (cached)
}

// f(t) on a packed {pred, tgt} pair. Vector mul/fma -> v_pk_* ; trans scalar.
__device__ __forceinline__ f2 f_lab2(f2 t) {
    const float T0 = 0.008856f;
    f2 lg;
    lg.x = __builtin_amdgcn_logf(t.x);          // log2; log(0)=-inf discarded by select
    lg.y = __builtin_amdgcn_logf(t.y);
    f2 e = lg * 0.33333333333333f;
    f2 cb;
    cb.x = __builtin_amdgcn_exp2f(e.x);         // cbrt(t) = exp2(log2(t)/3)
    cb.y = __builtin_amdgcn_exp2f(e.y);
    f2 lin = __builtin_elementwise_fma(f2{7.787f, 7.787f}, t,
                                       f2{16.0f / 116.0f, 16.0f / 116.0f});
    f2 r;
    r.x = (t.x > T0) ? cb.x : lin.x;
    r.y = (t.y > T0) ? cb.y : lin.y;
    return r;
}

// r,g,b packed {pred, tgt}. /XN,/ZN folded into matrix. L-branch removed:
// 116*f(y)-16 == 903.292*y on the linear branch (ref 903.3; diff ~1e-9 on loss),
// so L/100 = 1.16*f(y)-0.16 uniformly and dL = 1.16*(fy_p - fy_t).
__device__ __forceinline__ float pix_loss2(f2 r, f2 g, f2 b) {
    f2 x = __builtin_elementwise_fma(f2{0.433953f, 0.433953f}, r,
           __builtin_elementwise_fma(f2{0.376219f, 0.376219f}, g, b * 0.189828f));
    f2 y = __builtin_elementwise_fma(f2{0.212671f, 0.212671f}, r,
           __builtin_elementwise_fma(f2{0.715160f, 0.715160f}, g, b * 0.072169f));
    f2 z = __builtin_elementwise_fma(f2{0.017758f, 0.017758f}, r,
           __builtin_elementwise_fma(f2{0.109477f, 0.109477f}, g, b * 0.872766f));
    f2 fx = f_lab2(x);
    f2 fy = f_lab2(y);
    f2 fz = f_lab2(z);
    float u = fx.x - fx.y;        // fx_pred - fx_tgt
    float v = fy.x - fy.y;
    float w = fz.x - fz.y;
    float dL = 1.16f * v;
    float da = (u - v) * (500.0f / 255.0f);
    float db = (v - w) * (200.0f / 255.0f);
    return fmaf(dL, dL, fmaf(da, da, db * db));
}

__device__ __forceinline__ float quad_loss(const f4& pr, const f4& pg, const f4& pb,
                                           const f4& tr, const f4& tg, const f4& tb) {
    float a;
    a  = pix_loss2(f2{pr.x, tr.x}, f2{pg.x, tg.x}, f2{pb.x, tb.x});
    a += pix_loss2(f2{pr.y, tr.y}, f2{pg.y, tg.y}, f2{pb.y, tb.y});
    a += pix_loss2(f2{pr.z, tr.z}, f2{pg.z, tg.z}, f2{pb.z, tb.z});
    a += pix_loss2(f2{pr.w, tr.w}, f2{pg.w, tg.w}, f2{pb.w, tb.w});
    return a;
}

// MLP probe: 12 outstanding loads/thread, pairs 16B apart (same DRAM row /
// L2 sector). (256,6): VGPR cap ~85 so all 12 dwordx4 results stay live.
__global__ __launch_bounds__(BLOCK1, 6) void cc_partial(
        const float* __restrict__ pred,
        const float* __restrict__ tgt,
        float* __restrict__ part) {
    const int vb = blockIdx.x << 9;                    // block's first vec (512/block)
    const int batch = vb >> 16;                        // vb / HWV (uniform per block)
    const size_t ebase = (size_t)batch * BSTRIDE + (size_t)((vb & (HWV - 1)) << 2);

    const float* pp = pred + ebase + (threadIdx.x << 3);   // 8 floats per thread
    const float* tp = tgt  + ebase + (threadIdx.x << 3);

    // 12 upfront loads; each stream read as two ADJACENT dwordx4.
    const f4 pr0 = vload(pp);
    const f4 pr1 = vload(pp + 4);
    const f4 pg0 = vload(pp + CH);
    const f4 pg1 = vload(pp + CH + 4);
    const f4 pb0 = vload(pp + 2 * CH);
    const f4 pb1 = vload(pp + 2 * CH + 4);
    const f4 tr0 = vload(tp);
    const f4 tr1 = vload(tp + 4);
    const f4 tg0 = vload(tp + CH);
    const f4 tg1 = vload(tp + CH + 4);
    const f4 tb0 = vload(tp + 2 * CH);
    const f4 tb1 = vload(tp + 2 * CH + 4);

    float acc = quad_loss(pr0, pg0, pb0, tr0, tg0, tb0)
              + quad_loss(pr1, pg1, pb1, tr1, tg1, tb1);

    // wave (64-lane) shuffle reduce
    #pragma unroll
    for (int off = 32; off > 0; off >>= 1)
        acc += __shfl_down(acc, off);

    __shared__ float smem[BLOCK1 / 64];
    const int lane = threadIdx.x & 63;
    const int wid  = threadIdx.x >> 6;
    if (lane == 0) smem[wid] = acc;
    __syncthreads();
    if (threadIdx.x == 0) {
        float s = 0.0f;
        #pragma unroll
        for (int w = 0; w < BLOCK1 / 64; ++w) s += smem[w];
        part[blockIdx.x] = s;
    }
}

__global__ __launch_bounds__(256) void cc_final(
        const float* __restrict__ part,
        float* __restrict__ out) {
    // 2048 partials: thread t sums floats [8t, 8t+8) via two f4 loads.
    const float* p = part + (threadIdx.x << 3);
    f4 a0 = vload(p);
    f4 a1 = vload(p + 4);
    float acc = ((a0.x + a0.y) + (a0.z + a0.w)) + ((a1.x + a1.y) + (a1.z + a1.w));

    #pragma unroll
    for (int off = 32; off > 0; off >>= 1)
        acc += __shfl_down(acc, off);

    __shared__ float smem[4];
    const int lane = threadIdx.x & 63;
    const int wid  = threadIdx.x >> 6;
    if (lane == 0) smem[wid] = acc;
    __syncthreads();
    if (threadIdx.x == 0) {
        float s = smem[0] + smem[1] + smem[2] + smem[3];
        out[0] = s * NELEM_INV;   // WEIGHT = 1.0
    }
}

extern "C" void kernel_launch(void* const* d_in, const int* in_sizes, int n_in,
                              void* d_out, int out_size, void* d_ws, size_t ws_size,
                              hipStream_t stream) {
    const float* pred = (const float*)d_in[0];
    const float* tgt  = (const float*)d_in[1];
    float* out  = (float*)d_out;
    float* part = (float*)d_ws;   // 2048 floats = 8 KiB scratch

    cc_partial<<<GRID1, BLOCK1, 0, stream>>>(pred, tgt, part);
    cc_final<<<1, 256, 0, stream>>>(part, out);
}

// Round 15
// 25.264 us; speedup vs baseline: 1.0271x; 1.0271x over previous
//
#include <hip/hip_runtime.h>

// Problem constants (setup_inputs: [16, 3, 512, 512] fp32)
#define HW       262144     // 512*512
#define HWV      65536      // HW/4: float4 vecs per channel-image
#define CH       HW         // channel stride (elements)
#define BSTRIDE  (3*HW)     // batch stride (elements)
#define NELEM_INV (1.0f / 12582912.0f)   // 1 / (16*3*512*512)

#define GRID1    2048
#define BLOCK1   256
// Each thread: 2 ADJACENT f4 per stream (32B/lane) -> 12 outstanding loads/thread.
// Block covers 512 vecs = 2048 elems/stream; 512 | HWV -> no image straddle.

typedef float f4 __attribute__((ext_vector_type(4)));
typedef float f2 __attribute__((ext_vector_type(2)));

__device__ __forceinline__ f4 vload(const float* p) {
    return *reinterpret_cast<const f4*>(p);   // global_load_dwordx4 (cached)
}

// f(t) on a packed {pred, tgt} pair. Vector mul/fma -> v_pk_* ; trans scalar.
__device__ __forceinline__ f2 f_lab2(f2 t) {
    const float T0 = 0.008856f;
    f2 lg;
    lg.x = __builtin_amdgcn_logf(t.x);          // log2; log(0)=-inf discarded by select
    lg.y = __builtin_amdgcn_logf(t.y);
    f2 e = lg * 0.33333333333333f;
    f2 cb;
    cb.x = __builtin_amdgcn_exp2f(e.x);         // cbrt(t) = exp2(log2(t)/3)
    cb.y = __builtin_amdgcn_exp2f(e.y);
    f2 lin = __builtin_elementwise_fma(f2{7.787f, 7.787f}, t,
                                       f2{16.0f / 116.0f, 16.0f / 116.0f});
    f2 r;
    r.x = (t.x > T0) ? cb.x : lin.x;
    r.y = (t.y > T0) ? cb.y : lin.y;
    return r;
}

// r,g,b packed {pred, tgt}. /XN,/ZN folded into matrix. L-branch removed:
// 116*f(y)-16 == 903.292*y on the linear branch (ref 903.3; diff ~1e-9 on loss),
// so L/100 = 1.16*f(y)-0.16 uniformly and dL = 1.16*(fy_p - fy_t).
__device__ __forceinline__ float pix_loss2(f2 r, f2 g, f2 b) {
    f2 x = __builtin_elementwise_fma(f2{0.433953f, 0.433953f}, r,
           __builtin_elementwise_fma(f2{0.376219f, 0.376219f}, g, b * 0.189828f));
    f2 y = __builtin_elementwise_fma(f2{0.212671f, 0.212671f}, r,
           __builtin_elementwise_fma(f2{0.715160f, 0.715160f}, g, b * 0.072169f));
    f2 z = __builtin_elementwise_fma(f2{0.017758f, 0.017758f}, r,
           __builtin_elementwise_fma(f2{0.109477f, 0.109477f}, g, b * 0.872766f));
    f2 fx = f_lab2(x);
    f2 fy = f_lab2(y);
    f2 fz = f_lab2(z);
    float u = fx.x - fx.y;        // fx_pred - fx_tgt
    float v = fy.x - fy.y;
    float w = fz.x - fz.y;
    float dL = 1.16f * v;
    float da = (u - v) * (500.0f / 255.0f);
    float db = (v - w) * (200.0f / 255.0f);
    return fmaf(dL, dL, fmaf(da, da, db * db));
}

__device__ __forceinline__ float quad_loss(const f4& pr, const f4& pg, const f4& pb,
                                           const f4& tr, const f4& tg, const f4& tb) {
    float a;
    a  = pix_loss2(f2{pr.x, tr.x}, f2{pg.x, tg.x}, f2{pb.x, tb.x});
    a += pix_loss2(f2{pr.y, tr.y}, f2{pg.y, tg.y}, f2{pb.y, tb.y});
    a += pix_loss2(f2{pr.z, tr.z}, f2{pg.z, tg.z}, f2{pb.z, tb.z});
    a += pix_loss2(f2{pr.w, tr.w}, f2{pg.w, tg.w}, f2{pb.w, tb.w});
    return a;
}

// MLP probe: 12 outstanding loads/thread, pairs 16B apart (same DRAM row /
// L2 sector). (256,6): VGPR cap ~85 so all 12 dwordx4 results stay live.
__global__ __launch_bounds__(BLOCK1, 6) void cc_partial(
        const float* __restrict__ pred,
        const float* __restrict__ tgt,
        float* __restrict__ part) {
    const int vb = blockIdx.x << 9;                    // block's first vec (512/block)
    const int batch = vb >> 16;                        // vb / HWV (uniform per block)
    const size_t ebase = (size_t)batch * BSTRIDE + (size_t)((vb & (HWV - 1)) << 2);

    const float* pp = pred + ebase + (threadIdx.x << 3);   // 8 floats per thread
    const float* tp = tgt  + ebase + (threadIdx.x << 3);

    // 12 upfront loads; each stream read as two ADJACENT dwordx4.
    const f4 pr0 = vload(pp);
    const f4 pr1 = vload(pp + 4);
    const f4 pg0 = vload(pp + CH);
    const f4 pg1 = vload(pp + CH + 4);
    const f4 pb0 = vload(pp + 2 * CH);
    const f4 pb1 = vload(pp + 2 * CH + 4);
    const f4 tr0 = vload(tp);
    const f4 tr1 = vload(tp + 4);
    const f4 tg0 = vload(tp + CH);
    const f4 tg1 = vload(tp + CH + 4);
    const f4 tb0 = vload(tp + 2 * CH);
    const f4 tb1 = vload(tp + 2 * CH + 4);

    float acc = quad_loss(pr0, pg0, pb0, tr0, tg0, tb0)
              + quad_loss(pr1, pg1, pb1, tr1, tg1, tb1);

    // wave (64-lane) shuffle reduce
    #pragma unroll
    for (int off = 32; off > 0; off >>= 1)
        acc += __shfl_down(acc, off);

    __shared__ float smem[BLOCK1 / 64];
    const int lane = threadIdx.x & 63;
    const int wid  = threadIdx.x >> 6;
    if (lane == 0) smem[wid] = acc;
    __syncthreads();
    if (threadIdx.x == 0) {
        float s = 0.0f;
        #pragma unroll
        for (int w = 0; w < BLOCK1 / 64; ++w) s += smem[w];
        part[blockIdx.x] = s;
    }
}

__global__ __launch_bounds__(256) void cc_final(
        const float* __restrict__ part,
        float* __restrict__ out) {
    // 2048 partials: thread t sums floats [8t, 8t+8) via two f4 loads.
    const float* p = part + (threadIdx.x << 3);
    f4 a0 = vload(p);
    f4 a1 = vload(p + 4);
    float acc = ((a0.x + a0.y) + (a0.z + a0.w)) + ((a1.x + a1.y) + (a1.z + a1.w));

    #pragma unroll
    for (int off = 32; off > 0; off >>= 1)
        acc += __shfl_down(acc, off);

    __shared__ float smem[4];
    const int lane = threadIdx.x & 63;
    const int wid  = threadIdx.x >> 6;
    if (lane == 0) smem[wid] = acc;
    __syncthreads();
    if (threadIdx.x == 0) {
        float s = smem[0] + smem[1] + smem[2] + smem[3];
        out[0] = s * NELEM_INV;   // WEIGHT = 1.0
    }
}

extern "C" void kernel_launch(void* const* d_in, const int* in_sizes, int n_in,
                              void* d_out, int out_size, void* d_ws, size_t ws_size,
                              hipStream_t stream) {
    const float* pred = (const float*)d_in[0];
    const float* tgt  = (const float*)d_in[1];
    float* out  = (float*)d_out;
    float* part = (float*)d_ws;   // 2048 floats = 8 KiB scratch

    cc_partial<<<GRID1, BLOCK1, 0, stream>>>(pred, tgt, part);
    cc_final<<<1, 256, 0, stream>>>(part, out);
}

// Round 16
// 22.484 us; speedup vs baseline: 1.1542x; 1.1237x over previous
//
#include <hip/hip_runtime.h>

// Problem constants (setup_inputs: [16, 3, 512, 512] fp32)
#define HW       262144     // 512*512
#define HWV      65536      // HW/4: float4 vecs per channel-image
#define CH       HW         // channel stride (elements)
#define BSTRIDE  (3*HW)     // batch stride (elements)
#define NELEM_INV (1.0f / 12582912.0f)   // 1 / (16*3*512*512)

#define GRID1    1024
#define BLOCK1   1024       // 1024*1024*1 vec = NVEC exactly; 1024 | HWV -> no image straddle

typedef float f4 __attribute__((ext_vector_type(4)));
typedef float f2 __attribute__((ext_vector_type(2)));

__device__ __forceinline__ f4 vload(const float* p) {
    return *reinterpret_cast<const f4*>(p);   // global_load_dwordx4 (cached)
}

// f(t) on a packed {pred, tgt} pair. Vector mul/fma -> v_pk_* ; trans scalar.
__device__ __forceinline__ f2 f_lab2(f2 t) {
    const float T0 = 0.008856f;
    f2 lg;
    lg.x = __builtin_amdgcn_logf(t.x);          // log2; log(0)=-inf discarded by select
    lg.y = __builtin_amdgcn_logf(t.y);
    f2 e = lg * 0.33333333333333f;
    f2 cb;
    cb.x = __builtin_amdgcn_exp2f(e.x);         // cbrt(t) = exp2(log2(t)/3)
    cb.y = __builtin_amdgcn_exp2f(e.y);
    f2 lin = __builtin_elementwise_fma(f2{7.787f, 7.787f}, t,
                                       f2{16.0f / 116.0f, 16.0f / 116.0f});
    f2 r;
    r.x = (t.x > T0) ? cb.x : lin.x;
    r.y = (t.y > T0) ? cb.y : lin.y;
    return r;
}

// r,g,b packed {pred, tgt}. /XN,/ZN folded into matrix. L-branch removed:
// 116*f(y)-16 == 903.292*y on the linear branch (ref 903.3; diff ~1e-9 on loss),
// so L/100 = 1.16*f(y)-0.16 uniformly and dL = 1.16*(fy_p - fy_t).
__device__ __forceinline__ float pix_loss2(f2 r, f2 g, f2 b) {
    f2 x = __builtin_elementwise_fma(f2{0.433953f, 0.433953f}, r,
           __builtin_elementwise_fma(f2{0.376219f, 0.376219f}, g, b * 0.189828f));
    f2 y = __builtin_elementwise_fma(f2{0.212671f, 0.212671f}, r,
           __builtin_elementwise_fma(f2{0.715160f, 0.715160f}, g, b * 0.072169f));
    f2 z = __builtin_elementwise_fma(f2{0.017758f, 0.017758f}, r,
           __builtin_elementwise_fma(f2{0.109477f, 0.109477f}, g, b * 0.872766f));
    f2 fx = f_lab2(x);
    f2 fy = f_lab2(y);
    f2 fz = f_lab2(z);
    float u = fx.x - fx.y;        // fx_pred - fx_tgt
    float v = fy.x - fy.y;
    float w = fz.x - fz.y;
    float dL = 1.16f * v;
    float da = (u - v) * (500.0f / 255.0f);
    float db = (v - w) * (200.0f / 255.0f);
    return fmaf(dL, dL, fmaf(da, da, db * db));
}

__device__ __forceinline__ float quad_loss(const f4& pr, const f4& pg, const f4& pb,
                                           const f4& tr, const f4& tg, const f4& tb) {
    float a;
    a  = pix_loss2(f2{pr.x, tr.x}, f2{pg.x, tg.x}, f2{pb.x, tb.x});
    a += pix_loss2(f2{pr.y, tr.y}, f2{pg.y, tg.y}, f2{pb.y, tb.y});
    a += pix_loss2(f2{pr.z, tr.z}, f2{pg.z, tg.z}, f2{pb.z, tb.z});
    a += pix_loss2(f2{pr.w, tr.w}, f2{pg.w, tg.w}, f2{pb.w, tb.w});
    return a;
}

// Best-measured configuration (R12, 22.75 µs): one f4 vec per thread, 6
// upfront dwordx4 loads, 1024 blocks of 1024 threads, no loop.
__global__ __launch_bounds__(BLOCK1, 8) void cc_partial(
        const float* __restrict__ pred,
        const float* __restrict__ tgt,
        float* __restrict__ part) {
    // Block b owns vec range [b*1024, b*1024+1024) — one f4 vec per thread.
    const int vbase = blockIdx.x << 10;
    const int batch = vbase >> 16;                     // vbase / HWV (uniform per block)
    const size_t ebase = (size_t)batch * BSTRIDE + (size_t)((vbase & (HWV - 1)) << 2);

    const float* pp = pred + ebase + (threadIdx.x << 2);
    const float* tp = tgt  + ebase + (threadIdx.x << 2);

    const f4 pr = vload(pp);
    const f4 pg = vload(pp + CH);
    const f4 pb = vload(pp + 2 * CH);
    const f4 tr = vload(tp);
    const f4 tg = vload(tp + CH);
    const f4 tb = vload(tp + 2 * CH);

    float acc = quad_loss(pr, pg, pb, tr, tg, tb);

    // wave (64-lane) shuffle reduce
    #pragma unroll
    for (int off = 32; off > 0; off >>= 1)
        acc += __shfl_down(acc, off);

    __shared__ float smem[BLOCK1 / 64];
    const int lane = threadIdx.x & 63;
    const int wid  = threadIdx.x >> 6;
    if (lane == 0) smem[wid] = acc;
    __syncthreads();
    if (threadIdx.x == 0) {
        float s = 0.0f;
        #pragma unroll
        for (int w = 0; w < BLOCK1 / 64; ++w) s += smem[w];
        part[blockIdx.x] = s;
    }
}

__global__ __launch_bounds__(256) void cc_final(
        const float* __restrict__ part,
        float* __restrict__ out) {
    // 1024 partials: thread t sums floats [4t, 4t+4) via one f4 load.
    f4 a0 = vload(part + (threadIdx.x << 2));
    float acc = (a0.x + a0.y) + (a0.z + a0.w);

    #pragma unroll
    for (int off = 32; off > 0; off >>= 1)
        acc += __shfl_down(acc, off);

    __shared__ float smem[4];
    const int lane = threadIdx.x & 63;
    const int wid  = threadIdx.x >> 6;
    if (lane == 0) smem[wid] = acc;
    __syncthreads();
    if (threadIdx.x == 0) {
        float s = smem[0] + smem[1] + smem[2] + smem[3];
        out[0] = s * NELEM_INV;   // WEIGHT = 1.0
    }
}

extern "C" void kernel_launch(void* const* d_in, const int* in_sizes, int n_in,
                              void* d_out, int out_size, void* d_ws, size_t ws_size,
                              hipStream_t stream) {
    const float* pred = (const float*)d_in[0];
    const float* tgt  = (const float*)d_in[1];
    float* out  = (float*)d_out;
    float* part = (float*)d_ws;   // 1024 floats = 4 KiB scratch

    cc_partial<<<GRID1, BLOCK1, 0, stream>>>(pred, tgt, part);
    cc_final<<<1, 256, 0, stream>>>(part, out);
}